// Round 10
// baseline (238.632 us; speedup 1.0000x reference)
//
#include <hip/hip_runtime.h>

// Shape: (B=2, C=1, D=160, H=192, W=160) fp32. win=9/dim, win_size=9 (faithful bug).
#define B_ 2
#define D_ 160
#define H_ 192
#define W_ 160
#define W4_ (W_ / 4)                         // 40
#define HW_ (H_ * W_)                        // 30720
#define DHW_ (D_ * HW_)                      // 4,915,200
#define NV_ ((long long)B_ * D_ * H_ * W_)   // 9,830,400

#define YCH 4
#define NYC (H_ / YCH)     // 48

#define ROWS2 8
#define ZCH2 5
#define NZC2 (D_ / ZCH2)   // 32
#define PAD 4
#define LROW (W_ + 2 * PAD)  // 168

typedef _Float16 half4 __attribute__((ext_vector_type(4)));

__global__ void k_zero(double* acc) { *acc = 0.0; }

__device__ __forceinline__ void add4h(float4& d, const half4 v) {
    d.x += (float)v.x; d.y += (float)v.y; d.z += (float)v.z; d.w += (float)v.w;
}
__device__ __forceinline__ void sub4h(float4& d, const half4 v) {
    d.x -= (float)v.x; d.y -= (float)v.y; d.z -= (float)v.z; d.w -= (float)v.w;
}

// ---------------------------------------------------------------------------
// K1: y-direction 9-window sums of the 5 product maps, float4 along x,
// stored to A as fp16 (half4). One thread per (b, z, y-chunk, x4).
// A layout: [(b*5+c)*D + z][y][x] in _Float16.
// ---------------------------------------------------------------------------
__global__ void k1_ysum(const float* __restrict__ I, const float* __restrict__ J,
                        _Float16* __restrict__ A) {
    const int g = blockIdx.x * blockDim.x + threadIdx.x;
    const int ncol = B_ * D_ * NYC * W4_;    // 614,400
    if (g >= ncol) return;
    const int l  = g % W4_;
    int t = g / W4_;
    const int yc = t % NYC;  t /= NYC;
    const int z  = t % D_;
    const int b  = t / D_;
    const int y0 = yc * YCH;
    const int x4 = l * 4;

    const float* Ipf = I + ((size_t)(b * D_ + z) * H_) * W_ + x4;
    const float* Jpf = J + ((size_t)(b * D_ + z) * H_) * W_ + x4;
    _Float16* Ap = A + (size_t)(b * 5) * DHW_ + (size_t)z * HW_ + x4;

    float4 s0 = make_float4(0,0,0,0), s1 = s0, s2 = s0, s3 = s0, s4 = s0;
#pragma unroll
    for (int j = 0; j < 8; ++j) {            // prime window [y0-4, y0+3]
        const int yin = y0 - 4 + j;          // yin <= y0+3 <= 191 < H_ always
        if (yin >= 0) {
            const float4 a  = *(const float4*)(Ipf + (size_t)yin * W_);
            const float4 bb = *(const float4*)(Jpf + (size_t)yin * W_);
            s0.x += a.x;        s0.y += a.y;        s0.z += a.z;        s0.w += a.w;
            s1.x += bb.x;       s1.y += bb.y;       s1.z += bb.z;       s1.w += bb.w;
            s2.x += a.x*a.x;    s2.y += a.y*a.y;    s2.z += a.z*a.z;    s2.w += a.w*a.w;
            s3.x += bb.x*bb.x;  s3.y += bb.y*bb.y;  s3.z += bb.z*bb.z;  s3.w += bb.w*bb.w;
            s4.x += a.x*bb.x;   s4.y += a.y*bb.y;   s4.z += a.z*bb.z;   s4.w += a.w*bb.w;
        }
    }
#pragma unroll
    for (int k = 0; k < YCH; ++k) {
        const int yi = y0 + k + 4;           // leading edge
        if (yi < H_) {
            const float4 a  = *(const float4*)(Ipf + (size_t)yi * W_);
            const float4 bb = *(const float4*)(Jpf + (size_t)yi * W_);
            s0.x += a.x;        s0.y += a.y;        s0.z += a.z;        s0.w += a.w;
            s1.x += bb.x;       s1.y += bb.y;       s1.z += bb.z;       s1.w += bb.w;
            s2.x += a.x*a.x;    s2.y += a.y*a.y;    s2.z += a.z*a.z;    s2.w += a.w*a.w;
            s3.x += bb.x*bb.x;  s3.y += bb.y*bb.y;  s3.z += bb.z*bb.z;  s3.w += bb.w*bb.w;
            s4.x += a.x*bb.x;   s4.y += a.y*bb.y;   s4.z += a.z*bb.z;   s4.w += a.w*bb.w;
        }
        const int yo = y0 + k - 5;           // trailing edge
        if (yo >= 0) {
            const float4 a  = *(const float4*)(Ipf + (size_t)yo * W_);
            const float4 bb = *(const float4*)(Jpf + (size_t)yo * W_);
            s0.x -= a.x;        s0.y -= a.y;        s0.z -= a.z;        s0.w -= a.w;
            s1.x -= bb.x;       s1.y -= bb.y;       s1.z -= bb.z;       s1.w -= bb.w;
            s2.x -= a.x*a.x;    s2.y -= a.y*a.y;    s2.z -= a.z*a.z;    s2.w -= a.w*a.w;
            s3.x -= bb.x*bb.x;  s3.y -= bb.y*bb.y;  s3.z -= bb.z*bb.z;  s3.w -= bb.w*bb.w;
            s4.x -= a.x*bb.x;   s4.y -= a.y*bb.y;   s4.z -= a.z*bb.z;   s4.w -= a.w*bb.w;
        }
        const size_t o = (size_t)(y0 + k) * W_;
        half4 h0, h1, h2, h3, h4;
        h0.x = (_Float16)s0.x; h0.y = (_Float16)s0.y; h0.z = (_Float16)s0.z; h0.w = (_Float16)s0.w;
        h1.x = (_Float16)s1.x; h1.y = (_Float16)s1.y; h1.z = (_Float16)s1.z; h1.w = (_Float16)s1.w;
        h2.x = (_Float16)s2.x; h2.y = (_Float16)s2.y; h2.z = (_Float16)s2.z; h2.w = (_Float16)s2.w;
        h3.x = (_Float16)s3.x; h3.y = (_Float16)s3.y; h3.z = (_Float16)s3.z; h3.w = (_Float16)s3.w;
        h4.x = (_Float16)s4.x; h4.y = (_Float16)s4.y; h4.z = (_Float16)s4.z; h4.w = (_Float16)s4.w;
        *(half4*)(Ap + o)                      = h0;
        *(half4*)(Ap + o + 1 * (size_t)DHW_)   = h1;
        *(half4*)(Ap + o + 2 * (size_t)DHW_)   = h2;
        *(half4*)(Ap + o + 3 * (size_t)DHW_)   = h3;
        *(half4*)(Ap + o + 4 * (size_t)DHW_)   = h4;
    }
}

// ---------------------------------------------------------------------------
// K2: fused z-window sum (fp32 running sums over fp16 A) + x-window
// (3x float4 LDS reads per channel over a padded row) + cc + reduction.
// Block = 8 rows x 40 lanes (320 thr); thread owns 4 x-columns, marches a
// z-chunk of 5. Single-buffered LDS (26.9 KB -> 5 blocks/CU); grid 1536
// blocks = 6 blocks/CU for ~94% ideal occupancy.
// ---------------------------------------------------------------------------
__global__ void k2_zxcc(const _Float16* __restrict__ A, double* __restrict__ acc) {
    __shared__ float sbuf[ROWS2][5][LROW];   // 26.88 KB
    __shared__ float red[512];
    const int tid = threadIdx.x;             // 0..319
    const int r   = tid / W4_;               // 0..7
    const int l   = tid - r * W4_;           // 0..39
    const int x4  = l * 4;
    const int blk = blockIdx.x;
    const int zc  = blk % NZC2;
    const int rp  = blk / NZC2;              // 0..47
    const int gy  = rp * ROWS2 + r;          // 0..383  (192%8==0: no b straddle)
    const int b   = gy / H_;
    const int yy  = gy - b * H_;
    const int z0  = zc * ZCH2;

    {   // zero LDS once (pads must be 0; interior overwritten every step)
        float* p = &sbuf[0][0][0];
        for (int i = tid; i < ROWS2 * 5 * LROW; i += ROWS2 * W4_) p[i] = 0.f;
    }

    const _Float16* Abase = A + (size_t)(b * 5) * DHW_ + (size_t)yy * W_ + x4;

    float4 s[5];
#pragma unroll
    for (int c = 0; c < 5; ++c) s[c] = make_float4(0, 0, 0, 0);
#pragma unroll
    for (int j = 0; j < 8; ++j) {            // prime [z0-4, z0+3]; z0+3 <= 158 < D_
        const int zi = z0 - 4 + j;
        if (zi >= 0) {
#pragma unroll
            for (int c = 0; c < 5; ++c)
                add4h(s[c], *(const half4*)(Abase + (size_t)c * DHW_ + (size_t)zi * HW_));
        }
    }
    __syncthreads();                         // LDS zero visible

    float local = 0.f;
    for (int k = 0; k < ZCH2; ++k) {
        const int zi = z0 + k + 4;
        if (zi < D_) {
#pragma unroll
            for (int c = 0; c < 5; ++c)
                add4h(s[c], *(const half4*)(Abase + (size_t)c * DHW_ + (size_t)zi * HW_));
        }
        const int zo = z0 + k - 5;
        if (zo >= 0) {
#pragma unroll
            for (int c = 0; c < 5; ++c)
                sub4h(s[c], *(const half4*)(Abase + (size_t)c * DHW_ + (size_t)zo * HW_));
        }
#pragma unroll
        for (int c = 0; c < 5; ++c)
            *(float4*)&sbuf[r][c][PAD + x4] = s[c];
        __syncthreads();

        float4 S5[5];
#pragma unroll
        for (int c = 0; c < 5; ++c) {
            // window start (x4-4) sits at LDS index PAD+x4-4 = x4: aligned.
            const float4 a0 = *(const float4*)&sbuf[r][c][x4];
            const float4 a1 = *(const float4*)&sbuf[r][c][x4 + 4];
            const float4 a2 = *(const float4*)&sbuf[r][c][x4 + 8];
            const float o0 = a0.x + a0.y + a0.z + a0.w + a1.x + a1.y + a1.z + a1.w + a2.x;
            const float o1 = o0 - a0.x + a2.y;
            const float o2 = o1 - a0.y + a2.z;
            const float o3 = o2 - a0.z + a2.w;
            S5[c] = make_float4(o0, o1, o2, o3);
        }
        const float inv9 = 1.0f / 9.0f;
        {
            const float cr = S5[4].x - S5[1].x * S5[0].x * inv9;
            const float iv = S5[2].x - S5[0].x * S5[0].x * inv9;
            const float jv = S5[3].x - S5[1].x * S5[1].x * inv9;
            local += cr * cr / (iv * jv + 1e-5f);
        }
        {
            const float cr = S5[4].y - S5[1].y * S5[0].y * inv9;
            const float iv = S5[2].y - S5[0].y * S5[0].y * inv9;
            const float jv = S5[3].y - S5[1].y * S5[1].y * inv9;
            local += cr * cr / (iv * jv + 1e-5f);
        }
        {
            const float cr = S5[4].z - S5[1].z * S5[0].z * inv9;
            const float iv = S5[2].z - S5[0].z * S5[0].z * inv9;
            const float jv = S5[3].z - S5[1].z * S5[1].z * inv9;
            local += cr * cr / (iv * jv + 1e-5f);
        }
        {
            const float cr = S5[4].w - S5[1].w * S5[0].w * inv9;
            const float iv = S5[2].w - S5[0].w * S5[0].w * inv9;
            const float jv = S5[3].w - S5[1].w * S5[1].w * inv9;
            local += cr * cr / (iv * jv + 1e-5f);
        }
        __syncthreads();                     // WAR: next step overwrites sbuf
    }

    red[tid] = local;
    if (tid < 192) red[320 + tid] = 0.f;
    __syncthreads();
    for (int off = 256; off > 0; off >>= 1) {
        if (tid < off) red[tid] += red[tid + off];
        __syncthreads();
    }
    if (tid == 0) atomicAdd(acc, (double)red[0]);
}

// ---------------------------------------------------------------------------
// Fallback (workspace too small): direct clipped 9x9x9 sums per voxel.
// ---------------------------------------------------------------------------
__global__ void p_direct(const float* __restrict__ I, const float* __restrict__ J,
                         double* __restrict__ acc) {
    const long long idx = (long long)blockIdx.x * blockDim.x + threadIdx.x;
    float local = 0.f;
    if (idx < NV_) {
        const int x = (int)(idx % W_);
        long long t = idx / W_;
        const int y = (int)(t % H_);
        t /= H_;
        const int z = (int)(t % D_);
        const int b = (int)(t / D_);
        const int z0 = max(z - 4, 0), z1 = min(z + 4, D_ - 1);
        const int y0 = max(y - 4, 0), y1 = min(y + 4, H_ - 1);
        const int x0 = max(x - 4, 0), x1 = min(x + 4, W_ - 1);
        float sI = 0.f, sJ = 0.f, sI2 = 0.f, sJ2 = 0.f, sIJ = 0.f;
        for (int zz = z0; zz <= z1; ++zz)
            for (int yy = y0; yy <= y1; ++yy) {
                const size_t row = ((size_t)(b * D_ + zz) * H_ + yy) * W_;
                for (int xx = x0; xx <= x1; ++xx) {
                    const float a = I[row + xx];
                    const float bb = J[row + xx];
                    sI += a; sJ += bb; sI2 += a * a; sJ2 += bb * bb; sIJ += a * bb;
                }
            }
        const float inv9 = 1.0f / 9.0f;
        const float cross = sIJ - sJ * sI * inv9;
        const float iv    = sI2 - sI * sI * inv9;
        const float jv    = sJ2 - sJ * sJ * inv9;
        local = cross * cross / (iv * jv + 1e-5f);
    }
    __shared__ float red[256];
    red[threadIdx.x] = local;
    __syncthreads();
    for (int off = 128; off > 0; off >>= 1) {
        if (threadIdx.x < off) red[threadIdx.x] += red[threadIdx.x + off];
        __syncthreads();
    }
    if (threadIdx.x == 0) atomicAdd(acc, (double)red[0]);
}

__global__ void k_final(const double* __restrict__ acc, float* __restrict__ out) {
    out[0] = (float)(-(*acc) / (double)NV_);
}

extern "C" void kernel_launch(void* const* d_in, const int* in_sizes, int n_in,
                              void* d_out, int out_size, void* d_ws, size_t ws_size,
                              hipStream_t stream) {
    const float* I = (const float*)d_in[0];  // y_true
    const float* J = (const float*)d_in[1];  // y_pred
    float* out = (float*)d_out;

    const size_t needA = (size_t)5 * B_ * DHW_ * sizeof(_Float16);  // 98.3 MB
    if (ws_size >= 1024 + needA) {
        double* acc = (double*)d_ws;
        _Float16* A = (_Float16*)((char*)d_ws + 1024);
        k_zero<<<1, 1, 0, stream>>>(acc);
        const int ncol = B_ * D_ * NYC * W4_;
        k1_ysum<<<(ncol + 255) / 256, 256, 0, stream>>>(I, J, A);
        k2_zxcc<<<NZC2 * (B_ * H_ / ROWS2), ROWS2 * W4_, 0, stream>>>(A, acc);
        k_final<<<1, 1, 0, stream>>>(acc, out);
    } else if (ws_size >= sizeof(double)) {
        double* acc = (double*)d_ws;
        k_zero<<<1, 1, 0, stream>>>(acc);
        p_direct<<<(int)((NV_ + 255) / 256), 256, 0, stream>>>(I, J, acc);
        k_final<<<1, 1, 0, stream>>>(acc, out);
    }
}

// Round 11
// 110.485 us; speedup vs baseline: 2.1599x; 2.1599x over previous
//
#include <hip/hip_runtime.h>

// Shape: (B=2, C=1, D=160, H=192, W=160) fp32. win=9/dim, win_size=9 (faithful bug).
#define B_ 2
#define D_ 160
#define H_ 192
#define W_ 160
#define W4_ (W_ / 4)                         // 40
#define HW_ (H_ * W_)                        // 30720
#define DHW_ (D_ * HW_)                      // 4,915,200
#define NV_ ((long long)B_ * D_ * H_ * W_)   // 9,830,400

#define YCH 4
#define NYC (H_ / YCH)     // 48

#define ROWS2 8
#define ZCH2 10
#define NZC2 (D_ / ZCH2)   // 16
#define PAD 4
#define LROW (W_ + 2 * PAD)  // 168

// Interleaved A layout: [b][z][y][c][x] in _Float16.
//   c-stride = W_ (320 B), y-stride = 5*W_ (1600 B), z-stride = 5*HW_.
#define A_YSTRIDE ((size_t)5 * W_)
#define A_ZSTRIDE ((size_t)5 * HW_)

typedef _Float16 half4 __attribute__((ext_vector_type(4)));

__global__ void k_zero(double* acc) { *acc = 0.0; }

__device__ __forceinline__ void add4h(float4& d, const half4 v) {
    d.x += (float)v.x; d.y += (float)v.y; d.z += (float)v.z; d.w += (float)v.w;
}
__device__ __forceinline__ void sub4h(float4& d, const half4 v) {
    d.x -= (float)v.x; d.y -= (float)v.y; d.z -= (float)v.z; d.w -= (float)v.w;
}

// ---------------------------------------------------------------------------
// K1: y-direction 9-window sums of the 5 product maps, float4 along x,
// stored to interleaved fp16 A. One thread per (b, z, y-chunk, x4).
// Per (z,y) the wave's 5 channel stores cover ONE contiguous 1600 B region.
// ---------------------------------------------------------------------------
__global__ void k1_ysum(const float* __restrict__ I, const float* __restrict__ J,
                        _Float16* __restrict__ A) {
    const int g = blockIdx.x * blockDim.x + threadIdx.x;
    const int ncol = B_ * D_ * NYC * W4_;    // 614,400
    if (g >= ncol) return;
    const int l  = g % W4_;
    int t = g / W4_;
    const int yc = t % NYC;  t /= NYC;
    const int z  = t % D_;
    const int b  = t / D_;
    const int y0 = yc * YCH;
    const int x4 = l * 4;

    const float* Ipf = I + ((size_t)(b * D_ + z) * H_) * W_ + x4;
    const float* Jpf = J + ((size_t)(b * D_ + z) * H_) * W_ + x4;
    _Float16* Ap = A + (size_t)(b * D_ + z) * A_ZSTRIDE + x4;

    float4 s0 = make_float4(0,0,0,0), s1 = s0, s2 = s0, s3 = s0, s4 = s0;
#pragma unroll
    for (int j = 0; j < 8; ++j) {            // prime window [y0-4, y0+3]
        const int yin = y0 - 4 + j;          // yin <= y0+3 <= 191 < H_ always
        if (yin >= 0) {
            const float4 a  = *(const float4*)(Ipf + (size_t)yin * W_);
            const float4 bb = *(const float4*)(Jpf + (size_t)yin * W_);
            s0.x += a.x;        s0.y += a.y;        s0.z += a.z;        s0.w += a.w;
            s1.x += bb.x;       s1.y += bb.y;       s1.z += bb.z;       s1.w += bb.w;
            s2.x += a.x*a.x;    s2.y += a.y*a.y;    s2.z += a.z*a.z;    s2.w += a.w*a.w;
            s3.x += bb.x*bb.x;  s3.y += bb.y*bb.y;  s3.z += bb.z*bb.z;  s3.w += bb.w*bb.w;
            s4.x += a.x*bb.x;   s4.y += a.y*bb.y;   s4.z += a.z*bb.z;   s4.w += a.w*bb.w;
        }
    }
#pragma unroll
    for (int k = 0; k < YCH; ++k) {
        const int yi = y0 + k + 4;           // leading edge
        if (yi < H_) {
            const float4 a  = *(const float4*)(Ipf + (size_t)yi * W_);
            const float4 bb = *(const float4*)(Jpf + (size_t)yi * W_);
            s0.x += a.x;        s0.y += a.y;        s0.z += a.z;        s0.w += a.w;
            s1.x += bb.x;       s1.y += bb.y;       s1.z += bb.z;       s1.w += bb.w;
            s2.x += a.x*a.x;    s2.y += a.y*a.y;    s2.z += a.z*a.z;    s2.w += a.w*a.w;
            s3.x += bb.x*bb.x;  s3.y += bb.y*bb.y;  s3.z += bb.z*bb.z;  s3.w += bb.w*bb.w;
            s4.x += a.x*bb.x;   s4.y += a.y*bb.y;   s4.z += a.z*bb.z;   s4.w += a.w*bb.w;
        }
        const int yo = y0 + k - 5;           // trailing edge
        if (yo >= 0) {
            const float4 a  = *(const float4*)(Ipf + (size_t)yo * W_);
            const float4 bb = *(const float4*)(Jpf + (size_t)yo * W_);
            s0.x -= a.x;        s0.y -= a.y;        s0.z -= a.z;        s0.w -= a.w;
            s1.x -= bb.x;       s1.y -= bb.y;       s1.z -= bb.z;       s1.w -= bb.w;
            s2.x -= a.x*a.x;    s2.y -= a.y*a.y;    s2.z -= a.z*a.z;    s2.w -= a.w*a.w;
            s3.x -= bb.x*bb.x;  s3.y -= bb.y*bb.y;  s3.z -= bb.z*bb.z;  s3.w -= bb.w*bb.w;
            s4.x -= a.x*bb.x;   s4.y -= a.y*bb.y;   s4.z -= a.z*bb.z;   s4.w -= a.w*bb.w;
        }
        _Float16* Ay = Ap + (size_t)(y0 + k) * A_YSTRIDE;
        half4 h0, h1, h2, h3, h4;
        h0.x = (_Float16)s0.x; h0.y = (_Float16)s0.y; h0.z = (_Float16)s0.z; h0.w = (_Float16)s0.w;
        h1.x = (_Float16)s1.x; h1.y = (_Float16)s1.y; h1.z = (_Float16)s1.z; h1.w = (_Float16)s1.w;
        h2.x = (_Float16)s2.x; h2.y = (_Float16)s2.y; h2.z = (_Float16)s2.z; h2.w = (_Float16)s2.w;
        h3.x = (_Float16)s3.x; h3.y = (_Float16)s3.y; h3.z = (_Float16)s3.z; h3.w = (_Float16)s3.w;
        h4.x = (_Float16)s4.x; h4.y = (_Float16)s4.y; h4.z = (_Float16)s4.z; h4.w = (_Float16)s4.w;
        *(half4*)(Ay)           = h0;
        *(half4*)(Ay + 1 * W_)  = h1;
        *(half4*)(Ay + 2 * W_)  = h2;
        *(half4*)(Ay + 3 * W_)  = h3;
        *(half4*)(Ay + 4 * W_)  = h4;
    }
}

// ---------------------------------------------------------------------------
// K2: fused z-window sum (fp32 running sums over interleaved fp16 A) +
// x-window (3x float4 LDS reads per channel over a padded row) + cc +
// reduction. Block = 8 rows x 40 lanes (320 thr); thread owns 4 x-columns,
// marches a z-chunk of 10. Single-buffered LDS (26.9 KB).
// ---------------------------------------------------------------------------
__global__ void k2_zxcc(const _Float16* __restrict__ A, double* __restrict__ acc) {
    __shared__ float sbuf[ROWS2][5][LROW];   // 26.88 KB
    __shared__ float red[512];
    const int tid = threadIdx.x;             // 0..319
    const int r   = tid / W4_;               // 0..7
    const int l   = tid - r * W4_;           // 0..39
    const int x4  = l * 4;
    const int blk = blockIdx.x;
    const int zc  = blk % NZC2;
    const int rp  = blk / NZC2;              // 0..47
    const int gy  = rp * ROWS2 + r;          // 0..383  (192%8==0: no b straddle)
    const int b   = gy / H_;
    const int yy  = gy - b * H_;
    const int z0  = zc * ZCH2;

    {   // zero LDS once (pads must be 0; interior overwritten every step)
        float* p = &sbuf[0][0][0];
        for (int i = tid; i < ROWS2 * 5 * LROW; i += ROWS2 * W4_) p[i] = 0.f;
    }

    // per (b,y,x4) base; slice zi adds zi*A_ZSTRIDE, channel c adds c*W_.
    const _Float16* Abase = A + (size_t)b * D_ * A_ZSTRIDE + (size_t)yy * A_YSTRIDE + x4;

    float4 s[5];
#pragma unroll
    for (int c = 0; c < 5; ++c) s[c] = make_float4(0, 0, 0, 0);
#pragma unroll
    for (int j = 0; j < 8; ++j) {            // prime [z0-4, z0+3]; z0+3 <= 153 < D_
        const int zi = z0 - 4 + j;
        if (zi >= 0) {
            const _Float16* Az = Abase + (size_t)zi * A_ZSTRIDE;
#pragma unroll
            for (int c = 0; c < 5; ++c)
                add4h(s[c], *(const half4*)(Az + c * W_));
        }
    }
    __syncthreads();                         // LDS zero visible

    float local = 0.f;
    for (int k = 0; k < ZCH2; ++k) {
        const int zi = z0 + k + 4;
        if (zi < D_) {
            const _Float16* Az = Abase + (size_t)zi * A_ZSTRIDE;
#pragma unroll
            for (int c = 0; c < 5; ++c)
                add4h(s[c], *(const half4*)(Az + c * W_));
        }
        const int zo = z0 + k - 5;
        if (zo >= 0) {
            const _Float16* Az = Abase + (size_t)zo * A_ZSTRIDE;
#pragma unroll
            for (int c = 0; c < 5; ++c)
                sub4h(s[c], *(const half4*)(Az + c * W_));
        }
#pragma unroll
        for (int c = 0; c < 5; ++c)
            *(float4*)&sbuf[r][c][PAD + x4] = s[c];
        __syncthreads();

        float4 S5[5];
#pragma unroll
        for (int c = 0; c < 5; ++c) {
            // window start (x4-4) sits at LDS index PAD+x4-4 = x4: aligned.
            const float4 a0 = *(const float4*)&sbuf[r][c][x4];
            const float4 a1 = *(const float4*)&sbuf[r][c][x4 + 4];
            const float4 a2 = *(const float4*)&sbuf[r][c][x4 + 8];
            const float o0 = a0.x + a0.y + a0.z + a0.w + a1.x + a1.y + a1.z + a1.w + a2.x;
            const float o1 = o0 - a0.x + a2.y;
            const float o2 = o1 - a0.y + a2.z;
            const float o3 = o2 - a0.z + a2.w;
            S5[c] = make_float4(o0, o1, o2, o3);
        }
        const float inv9 = 1.0f / 9.0f;
        {
            const float cr = S5[4].x - S5[1].x * S5[0].x * inv9;
            const float iv = S5[2].x - S5[0].x * S5[0].x * inv9;
            const float jv = S5[3].x - S5[1].x * S5[1].x * inv9;
            local += cr * cr / (iv * jv + 1e-5f);
        }
        {
            const float cr = S5[4].y - S5[1].y * S5[0].y * inv9;
            const float iv = S5[2].y - S5[0].y * S5[0].y * inv9;
            const float jv = S5[3].y - S5[1].y * S5[1].y * inv9;
            local += cr * cr / (iv * jv + 1e-5f);
        }
        {
            const float cr = S5[4].z - S5[1].z * S5[0].z * inv9;
            const float iv = S5[2].z - S5[0].z * S5[0].z * inv9;
            const float jv = S5[3].z - S5[1].z * S5[1].z * inv9;
            local += cr * cr / (iv * jv + 1e-5f);
        }
        {
            const float cr = S5[4].w - S5[1].w * S5[0].w * inv9;
            const float iv = S5[2].w - S5[0].w * S5[0].w * inv9;
            const float jv = S5[3].w - S5[1].w * S5[1].w * inv9;
            local += cr * cr / (iv * jv + 1e-5f);
        }
        __syncthreads();                     // WAR: next step overwrites sbuf
    }

    red[tid] = local;
    if (tid < 192) red[320 + tid] = 0.f;
    __syncthreads();
    for (int off = 256; off > 0; off >>= 1) {
        if (tid < off) red[tid] += red[tid + off];
        __syncthreads();
    }
    if (tid == 0) atomicAdd(acc, (double)red[0]);
}

// ---------------------------------------------------------------------------
// Fallback (workspace too small): direct clipped 9x9x9 sums per voxel.
// ---------------------------------------------------------------------------
__global__ void p_direct(const float* __restrict__ I, const float* __restrict__ J,
                         double* __restrict__ acc) {
    const long long idx = (long long)blockIdx.x * blockDim.x + threadIdx.x;
    float local = 0.f;
    if (idx < NV_) {
        const int x = (int)(idx % W_);
        long long t = idx / W_;
        const int y = (int)(t % H_);
        t /= H_;
        const int z = (int)(t % D_);
        const int b = (int)(t / D_);
        const int z0 = max(z - 4, 0), z1 = min(z + 4, D_ - 1);
        const int y0 = max(y - 4, 0), y1 = min(y + 4, H_ - 1);
        const int x0 = max(x - 4, 0), x1 = min(x + 4, W_ - 1);
        float sI = 0.f, sJ = 0.f, sI2 = 0.f, sJ2 = 0.f, sIJ = 0.f;
        for (int zz = z0; zz <= z1; ++zz)
            for (int yy = y0; yy <= y1; ++yy) {
                const size_t row = ((size_t)(b * D_ + zz) * H_ + yy) * W_;
                for (int xx = x0; xx <= x1; ++xx) {
                    const float a = I[row + xx];
                    const float bb = J[row + xx];
                    sI += a; sJ += bb; sI2 += a * a; sJ2 += bb * bb; sIJ += a * bb;
                }
            }
        const float inv9 = 1.0f / 9.0f;
        const float cross = sIJ - sJ * sI * inv9;
        const float iv    = sI2 - sI * sI * inv9;
        const float jv    = sJ2 - sJ * sJ * inv9;
        local = cross * cross / (iv * jv + 1e-5f);
    }
    __shared__ float red[256];
    red[threadIdx.x] = local;
    __syncthreads();
    for (int off = 128; off > 0; off >>= 1) {
        if (threadIdx.x < off) red[threadIdx.x] += red[threadIdx.x + off];
        __syncthreads();
    }
    if (threadIdx.x == 0) atomicAdd(acc, (double)red[0]);
}

__global__ void k_final(const double* __restrict__ acc, float* __restrict__ out) {
    out[0] = (float)(-(*acc) / (double)NV_);
}

extern "C" void kernel_launch(void* const* d_in, const int* in_sizes, int n_in,
                              void* d_out, int out_size, void* d_ws, size_t ws_size,
                              hipStream_t stream) {
    const float* I = (const float*)d_in[0];  // y_true
    const float* J = (const float*)d_in[1];  // y_pred
    float* out = (float*)d_out;

    const size_t needA = (size_t)5 * B_ * DHW_ * sizeof(_Float16);  // 98.3 MB
    if (ws_size >= 1024 + needA) {
        double* acc = (double*)d_ws;
        _Float16* A = (_Float16*)((char*)d_ws + 1024);
        k_zero<<<1, 1, 0, stream>>>(acc);
        const int ncol = B_ * D_ * NYC * W4_;
        k1_ysum<<<(ncol + 255) / 256, 256, 0, stream>>>(I, J, A);
        k2_zxcc<<<NZC2 * (B_ * H_ / ROWS2), ROWS2 * W4_, 0, stream>>>(A, acc);
        k_final<<<1, 1, 0, stream>>>(acc, out);
    } else if (ws_size >= sizeof(double)) {
        double* acc = (double*)d_ws;
        k_zero<<<1, 1, 0, stream>>>(acc);
        p_direct<<<(int)((NV_ + 255) / 256), 256, 0, stream>>>(I, J, acc);
        k_final<<<1, 1, 0, stream>>>(acc, out);
    }
}

// Round 12
// 108.375 us; speedup vs baseline: 2.2019x; 1.0195x over previous
//
#include <hip/hip_runtime.h>

// Shape: (B=2, C=1, D=160, H=192, W=160) fp32. win=9/dim, win_size=9 (faithful bug).
#define B_ 2
#define D_ 160
#define H_ 192
#define W_ 160
#define W4_ (W_ / 4)                         // 40
#define W8_ (W_ / 8)                         // 20
#define HW_ (H_ * W_)                        // 30720
#define DHW_ (D_ * HW_)                      // 4,915,200
#define NV_ ((long long)B_ * D_ * H_ * W_)   // 9,830,400

#define YCH 4
#define NYC (H_ / YCH)     // 48

#define ROWS2 8
#define ZCH2 10
#define NZC2 (D_ / ZCH2)   // 16
#define PAD 4
#define LROW (W_ + 2 * PAD)  // 168

// Interleaved A layout: [b][z][y][c][x] in _Float16.
#define A_YSTRIDE ((size_t)5 * W_)
#define A_ZSTRIDE ((size_t)5 * HW_)

typedef _Float16 half4 __attribute__((ext_vector_type(4)));
typedef _Float16 half8 __attribute__((ext_vector_type(8)));

__global__ void k_zero(double* acc) { *acc = 0.0; }

__device__ __forceinline__ void add4h(float4& d, const half4 v) {
    d.x += (float)v.x; d.y += (float)v.y; d.z += (float)v.z; d.w += (float)v.w;
}
__device__ __forceinline__ void sub4h(float4& d, const half4 v) {
    d.x -= (float)v.x; d.y -= (float)v.y; d.z -= (float)v.z; d.w -= (float)v.w;
}

// Accumulate (SGN=+1/-1) one row's products into the 10 float4 partials.
template<int SGN>
__device__ __forceinline__ void acc_row(float4 sA[5], float4 sB[5],
                                        const float* __restrict__ Ipf,
                                        const float* __restrict__ Jpf,
                                        size_t off) {
    const float4 a1  = *(const float4*)(Ipf + off);
    const float4 a2  = *(const float4*)(Ipf + off + 4);
    const float4 b1  = *(const float4*)(Jpf + off);
    const float4 b2  = *(const float4*)(Jpf + off + 4);
    if (SGN > 0) {
        sA[0].x += a1.x;      sA[0].y += a1.y;      sA[0].z += a1.z;      sA[0].w += a1.w;
        sB[0].x += a2.x;      sB[0].y += a2.y;      sB[0].z += a2.z;      sB[0].w += a2.w;
        sA[1].x += b1.x;      sA[1].y += b1.y;      sA[1].z += b1.z;      sA[1].w += b1.w;
        sB[1].x += b2.x;      sB[1].y += b2.y;      sB[1].z += b2.z;      sB[1].w += b2.w;
        sA[2].x += a1.x*a1.x; sA[2].y += a1.y*a1.y; sA[2].z += a1.z*a1.z; sA[2].w += a1.w*a1.w;
        sB[2].x += a2.x*a2.x; sB[2].y += a2.y*a2.y; sB[2].z += a2.z*a2.z; sB[2].w += a2.w*a2.w;
        sA[3].x += b1.x*b1.x; sA[3].y += b1.y*b1.y; sA[3].z += b1.z*b1.z; sA[3].w += b1.w*b1.w;
        sB[3].x += b2.x*b2.x; sB[3].y += b2.y*b2.y; sB[3].z += b2.z*b2.z; sB[3].w += b2.w*b2.w;
        sA[4].x += a1.x*b1.x; sA[4].y += a1.y*b1.y; sA[4].z += a1.z*b1.z; sA[4].w += a1.w*b1.w;
        sB[4].x += a2.x*b2.x; sB[4].y += a2.y*b2.y; sB[4].z += a2.z*b2.z; sB[4].w += a2.w*b2.w;
    } else {
        sA[0].x -= a1.x;      sA[0].y -= a1.y;      sA[0].z -= a1.z;      sA[0].w -= a1.w;
        sB[0].x -= a2.x;      sB[0].y -= a2.y;      sB[0].z -= a2.z;      sB[0].w -= a2.w;
        sA[1].x -= b1.x;      sA[1].y -= b1.y;      sA[1].z -= b1.z;      sA[1].w -= b1.w;
        sB[1].x -= b2.x;      sB[1].y -= b2.y;      sB[1].z -= b2.z;      sB[1].w -= b2.w;
        sA[2].x -= a1.x*a1.x; sA[2].y -= a1.y*a1.y; sA[2].z -= a1.z*a1.z; sA[2].w -= a1.w*a1.w;
        sB[2].x -= a2.x*a2.x; sB[2].y -= a2.y*a2.y; sB[2].z -= a2.z*a2.z; sB[2].w -= a2.w*a2.w;
        sA[3].x -= b1.x*b1.x; sA[3].y -= b1.y*b1.y; sA[3].z -= b1.z*b1.z; sA[3].w -= b1.w*b1.w;
        sB[3].x -= b2.x*b2.x; sB[3].y -= b2.y*b2.y; sB[3].z -= b2.z*b2.z; sB[3].w -= b2.w*b2.w;
        sA[4].x -= a1.x*b1.x; sA[4].y -= a1.y*b1.y; sA[4].z -= a1.z*b1.z; sA[4].w -= a1.w*b1.w;
        sB[4].x -= a2.x*b2.x; sB[4].y -= a2.y*b2.y; sB[4].z -= a2.z*b2.z; sB[4].w -= a2.w*b2.w;
    }
}

// ---------------------------------------------------------------------------
// K1: y-direction 9-window sums of the 5 product maps. Each thread owns 8
// consecutive x (2x float4 loads per map per row, one 16B half8 store per
// channel). One thread per (b, z, y-chunk, x8).
// ---------------------------------------------------------------------------
__global__ void k1_ysum(const float* __restrict__ I, const float* __restrict__ J,
                        _Float16* __restrict__ A) {
    const int g = blockIdx.x * blockDim.x + threadIdx.x;
    const int ncol = B_ * D_ * NYC * W8_;    // 307,200
    if (g >= ncol) return;
    const int l  = g % W8_;
    int t = g / W8_;
    const int yc = t % NYC;  t /= NYC;
    const int z  = t % D_;
    const int b  = t / D_;
    const int y0 = yc * YCH;
    const int x8 = l * 8;

    const float* Ipf = I + ((size_t)(b * D_ + z) * H_) * W_ + x8;
    const float* Jpf = J + ((size_t)(b * D_ + z) * H_) * W_ + x8;
    _Float16* Ap = A + (size_t)(b * D_ + z) * A_ZSTRIDE + x8;

    float4 sA[5], sB[5];
#pragma unroll
    for (int c = 0; c < 5; ++c) { sA[c] = make_float4(0,0,0,0); sB[c] = make_float4(0,0,0,0); }

#pragma unroll
    for (int j = 0; j < 8; ++j) {            // prime window [y0-4, y0+3]
        const int yin = y0 - 4 + j;          // yin <= y0+3 <= 191 < H_ always
        if (yin >= 0) acc_row<+1>(sA, sB, Ipf, Jpf, (size_t)yin * W_);
    }
#pragma unroll
    for (int k = 0; k < YCH; ++k) {
        const int yi = y0 + k + 4;           // leading edge
        if (yi < H_) acc_row<+1>(sA, sB, Ipf, Jpf, (size_t)yi * W_);
        const int yo = y0 + k - 5;           // trailing edge
        if (yo >= 0) acc_row<-1>(sA, sB, Ipf, Jpf, (size_t)yo * W_);

        _Float16* Ay = Ap + (size_t)(y0 + k) * A_YSTRIDE;
#pragma unroll
        for (int c = 0; c < 5; ++c) {
            half8 h;
            h[0] = (_Float16)sA[c].x; h[1] = (_Float16)sA[c].y;
            h[2] = (_Float16)sA[c].z; h[3] = (_Float16)sA[c].w;
            h[4] = (_Float16)sB[c].x; h[5] = (_Float16)sB[c].y;
            h[6] = (_Float16)sB[c].z; h[7] = (_Float16)sB[c].w;
            *(half8*)(Ay + c * W_) = h;
        }
    }
}

// ---------------------------------------------------------------------------
// K2: fused z-window sum (fp32 running sums over interleaved fp16 A) +
// x-window (3x float4 LDS reads per channel over a padded row) + cc +
// reduction. Block = 8 rows x 40 lanes (320 thr); thread owns 4 x-columns,
// marches a z-chunk of 10. Single-buffered LDS (26.9 KB).
// ---------------------------------------------------------------------------
__global__ void k2_zxcc(const _Float16* __restrict__ A, double* __restrict__ acc) {
    __shared__ float sbuf[ROWS2][5][LROW];   // 26.88 KB
    __shared__ float red[512];
    const int tid = threadIdx.x;             // 0..319
    const int r   = tid / W4_;               // 0..7
    const int l   = tid - r * W4_;           // 0..39
    const int x4  = l * 4;
    const int blk = blockIdx.x;
    const int zc  = blk % NZC2;
    const int rp  = blk / NZC2;              // 0..47
    const int gy  = rp * ROWS2 + r;          // 0..383  (192%8==0: no b straddle)
    const int b   = gy / H_;
    const int yy  = gy - b * H_;
    const int z0  = zc * ZCH2;

    {   // zero LDS once (pads must be 0; interior overwritten every step)
        float* p = &sbuf[0][0][0];
        for (int i = tid; i < ROWS2 * 5 * LROW; i += ROWS2 * W4_) p[i] = 0.f;
    }

    const _Float16* Abase = A + (size_t)b * D_ * A_ZSTRIDE + (size_t)yy * A_YSTRIDE + x4;

    float4 s[5];
#pragma unroll
    for (int c = 0; c < 5; ++c) s[c] = make_float4(0, 0, 0, 0);
#pragma unroll
    for (int j = 0; j < 8; ++j) {            // prime [z0-4, z0+3]; z0+3 <= 153 < D_
        const int zi = z0 - 4 + j;
        if (zi >= 0) {
            const _Float16* Az = Abase + (size_t)zi * A_ZSTRIDE;
#pragma unroll
            for (int c = 0; c < 5; ++c)
                add4h(s[c], *(const half4*)(Az + c * W_));
        }
    }
    __syncthreads();                         // LDS zero visible

    float local = 0.f;
    for (int k = 0; k < ZCH2; ++k) {
        const int zi = z0 + k + 4;
        if (zi < D_) {
            const _Float16* Az = Abase + (size_t)zi * A_ZSTRIDE;
#pragma unroll
            for (int c = 0; c < 5; ++c)
                add4h(s[c], *(const half4*)(Az + c * W_));
        }
        const int zo = z0 + k - 5;
        if (zo >= 0) {
            const _Float16* Az = Abase + (size_t)zo * A_ZSTRIDE;
#pragma unroll
            for (int c = 0; c < 5; ++c)
                sub4h(s[c], *(const half4*)(Az + c * W_));
        }
#pragma unroll
        for (int c = 0; c < 5; ++c)
            *(float4*)&sbuf[r][c][PAD + x4] = s[c];
        __syncthreads();

        float4 S5[5];
#pragma unroll
        for (int c = 0; c < 5; ++c) {
            const float4 a0 = *(const float4*)&sbuf[r][c][x4];
            const float4 a1 = *(const float4*)&sbuf[r][c][x4 + 4];
            const float4 a2 = *(const float4*)&sbuf[r][c][x4 + 8];
            const float o0 = a0.x + a0.y + a0.z + a0.w + a1.x + a1.y + a1.z + a1.w + a2.x;
            const float o1 = o0 - a0.x + a2.y;
            const float o2 = o1 - a0.y + a2.z;
            const float o3 = o2 - a0.z + a2.w;
            S5[c] = make_float4(o0, o1, o2, o3);
        }
        const float inv9 = 1.0f / 9.0f;
        {
            const float cr = S5[4].x - S5[1].x * S5[0].x * inv9;
            const float iv = S5[2].x - S5[0].x * S5[0].x * inv9;
            const float jv = S5[3].x - S5[1].x * S5[1].x * inv9;
            local += cr * cr / (iv * jv + 1e-5f);
        }
        {
            const float cr = S5[4].y - S5[1].y * S5[0].y * inv9;
            const float iv = S5[2].y - S5[0].y * S5[0].y * inv9;
            const float jv = S5[3].y - S5[1].y * S5[1].y * inv9;
            local += cr * cr / (iv * jv + 1e-5f);
        }
        {
            const float cr = S5[4].z - S5[1].z * S5[0].z * inv9;
            const float iv = S5[2].z - S5[0].z * S5[0].z * inv9;
            const float jv = S5[3].z - S5[1].z * S5[1].z * inv9;
            local += cr * cr / (iv * jv + 1e-5f);
        }
        {
            const float cr = S5[4].w - S5[1].w * S5[0].w * inv9;
            const float iv = S5[2].w - S5[0].w * S5[0].w * inv9;
            const float jv = S5[3].w - S5[1].w * S5[1].w * inv9;
            local += cr * cr / (iv * jv + 1e-5f);
        }
        __syncthreads();                     // WAR: next step overwrites sbuf
    }

    red[tid] = local;
    if (tid < 192) red[320 + tid] = 0.f;
    __syncthreads();
    for (int off = 256; off > 0; off >>= 1) {
        if (tid < off) red[tid] += red[tid + off];
        __syncthreads();
    }
    if (tid == 0) atomicAdd(acc, (double)red[0]);
}

// ---------------------------------------------------------------------------
// Fallback (workspace too small): direct clipped 9x9x9 sums per voxel.
// ---------------------------------------------------------------------------
__global__ void p_direct(const float* __restrict__ I, const float* __restrict__ J,
                         double* __restrict__ acc) {
    const long long idx = (long long)blockIdx.x * blockDim.x + threadIdx.x;
    float local = 0.f;
    if (idx < NV_) {
        const int x = (int)(idx % W_);
        long long t = idx / W_;
        const int y = (int)(t % H_);
        t /= H_;
        const int z = (int)(t % D_);
        const int b = (int)(t / D_);
        const int z0 = max(z - 4, 0), z1 = min(z + 4, D_ - 1);
        const int y0 = max(y - 4, 0), y1 = min(y + 4, H_ - 1);
        const int x0 = max(x - 4, 0), x1 = min(x + 4, W_ - 1);
        float sI = 0.f, sJ = 0.f, sI2 = 0.f, sJ2 = 0.f, sIJ = 0.f;
        for (int zz = z0; zz <= z1; ++zz)
            for (int yy = y0; yy <= y1; ++yy) {
                const size_t row = ((size_t)(b * D_ + zz) * H_ + yy) * W_;
                for (int xx = x0; xx <= x1; ++xx) {
                    const float a = I[row + xx];
                    const float bb = J[row + xx];
                    sI += a; sJ += bb; sI2 += a * a; sJ2 += bb * bb; sIJ += a * bb;
                }
            }
        const float inv9 = 1.0f / 9.0f;
        const float cross = sIJ - sJ * sI * inv9;
        const float iv    = sI2 - sI * sI * inv9;
        const float jv    = sJ2 - sJ * sJ * inv9;
        local = cross * cross / (iv * jv + 1e-5f);
    }
    __shared__ float red[256];
    red[threadIdx.x] = local;
    __syncthreads();
    for (int off = 128; off > 0; off >>= 1) {
        if (threadIdx.x < off) red[threadIdx.x] += red[threadIdx.x + off];
        __syncthreads();
    }
    if (threadIdx.x == 0) atomicAdd(acc, (double)red[0]);
}

__global__ void k_final(const double* __restrict__ acc, float* __restrict__ out) {
    out[0] = (float)(-(*acc) / (double)NV_);
}

extern "C" void kernel_launch(void* const* d_in, const int* in_sizes, int n_in,
                              void* d_out, int out_size, void* d_ws, size_t ws_size,
                              hipStream_t stream) {
    const float* I = (const float*)d_in[0];  // y_true
    const float* J = (const float*)d_in[1];  // y_pred
    float* out = (float*)d_out;

    const size_t needA = (size_t)5 * B_ * DHW_ * sizeof(_Float16);  // 98.3 MB
    if (ws_size >= 1024 + needA) {
        double* acc = (double*)d_ws;
        _Float16* A = (_Float16*)((char*)d_ws + 1024);
        k_zero<<<1, 1, 0, stream>>>(acc);
        const int ncol = B_ * D_ * NYC * W8_;
        k1_ysum<<<(ncol + 255) / 256, 256, 0, stream>>>(I, J, A);
        k2_zxcc<<<NZC2 * (B_ * H_ / ROWS2), ROWS2 * W4_, 0, stream>>>(A, acc);
        k_final<<<1, 1, 0, stream>>>(acc, out);
    } else if (ws_size >= sizeof(double)) {
        double* acc = (double*)d_ws;
        k_zero<<<1, 1, 0, stream>>>(acc);
        p_direct<<<(int)((NV_ + 255) / 256), 256, 0, stream>>>(I, J, acc);
        k_final<<<1, 1, 0, stream>>>(acc, out);
    }
}

// Round 13
// 81.789 us; speedup vs baseline: 2.9177x; 1.3251x over previous
//
#include <hip/hip_runtime.h>

// Shape: (B=2, C=1, D=160, H=192, W=160) fp32. win=9/dim, win_size=9 (faithful bug).
#define B_ 2
#define D_ 160
#define H_ 192
#define W_ 160
#define W4_ (W_ / 4)                         // 40
#define HW_ (H_ * W_)                        // 30720
#define DHW_ (D_ * HW_)                      // 4,915,200
#define NV_ ((long long)B_ * D_ * H_ * W_)   // 9,830,400

// K1 tiling: block = one (b,z) slice x 32-wide x-tile, full H staged in LDS.
#define XT 32
#define NXT (W_ / XT)       // 5
#define YCH1 6
#define NYC1 (H_ / YCH1)    // 32
#define SPAD 4              // LDS row pad (halves) -> stride 36 h = 18 banks

#define ROWS2 8
#define ZCH2 10
#define NZC2 (D_ / ZCH2)    // 16
#define PAD 4
#define LROW (W_ + 2 * PAD) // 168

// Interleaved A layout: [b][z][y][c][x] in _Float16.
#define A_YSTRIDE ((size_t)5 * W_)
#define A_ZSTRIDE ((size_t)5 * HW_)

typedef _Float16 half4 __attribute__((ext_vector_type(4)));

__global__ void k_zero(double* acc) { *acc = 0.0; }

__device__ __forceinline__ void add4h(float4& d, const half4 v) {
    d.x += (float)v.x; d.y += (float)v.y; d.z += (float)v.z; d.w += (float)v.w;
}
__device__ __forceinline__ void sub4h(float4& d, const half4 v) {
    d.x -= (float)v.x; d.y -= (float)v.y; d.z -= (float)v.z; d.w -= (float)v.w;
}

// Accumulate (+/-) one staged row's 5 products into s[5] (4 x-cols).
template<int SGN>
__device__ __forceinline__ void acc_lds(float4 s[5], const half4 ha, const half4 hb) {
    const float4 a = make_float4((float)ha.x, (float)ha.y, (float)ha.z, (float)ha.w);
    const float4 b = make_float4((float)hb.x, (float)hb.y, (float)hb.z, (float)hb.w);
    if (SGN > 0) {
        s[0].x += a.x;     s[0].y += a.y;     s[0].z += a.z;     s[0].w += a.w;
        s[1].x += b.x;     s[1].y += b.y;     s[1].z += b.z;     s[1].w += b.w;
        s[2].x += a.x*a.x; s[2].y += a.y*a.y; s[2].z += a.z*a.z; s[2].w += a.w*a.w;
        s[3].x += b.x*b.x; s[3].y += b.y*b.y; s[3].z += b.z*b.z; s[3].w += b.w*b.w;
        s[4].x += a.x*b.x; s[4].y += a.y*b.y; s[4].z += a.z*b.z; s[4].w += a.w*b.w;
    } else {
        s[0].x -= a.x;     s[0].y -= a.y;     s[0].z -= a.z;     s[0].w -= a.w;
        s[1].x -= b.x;     s[1].y -= b.y;     s[1].z -= b.z;     s[1].w -= b.w;
        s[2].x -= a.x*a.x; s[2].y -= a.y*a.y; s[2].z -= a.z*a.z; s[2].w -= a.w*a.w;
        s[3].x -= b.x*b.x; s[3].y -= b.y*b.y; s[3].z -= b.z*b.z; s[3].w -= b.w*b.w;
        s[4].x -= a.x*b.x; s[4].y -= a.y*b.y; s[4].z -= a.z*b.z; s[4].w -= a.w*b.w;
    }
}

// ---------------------------------------------------------------------------
// K1: stage one (b,z) slice's 32-wide x-column pair (I,J, full H=192) into
// LDS as fp16 ONCE (read-amplification 1.0, deep MLP), then 8x32 threads run
// y-window running sums from LDS and store interleaved fp16 A.
// ---------------------------------------------------------------------------
__global__ __launch_bounds__(256) void k1_ysum(const float* __restrict__ I,
                                               const float* __restrict__ J,
                                               _Float16* __restrict__ A) {
    __shared__ _Float16 sI[H_][XT + SPAD];   // 13.8 KB
    __shared__ _Float16 sJ[H_][XT + SPAD];   // 13.8 KB
    const int tid = threadIdx.x;             // 0..255
    const int xt  = blockIdx.x % NXT;
    const int bz  = blockIdx.x / NXT;        // b*D + z
    const int x0  = xt * XT;

    const float* Ibase = I + (size_t)bz * HW_ + x0;
    const float* Jbase = J + (size_t)bz * HW_ + x0;

    // ---- stage: 1536 float4 per map, 6 per thread per map ----
#pragma unroll
    for (int i = 0; i < 6; ++i) {
        const int idx = i * 256 + tid;       // 0..1535
        const int row = idx >> 3;            // /8 groups per row
        const int g   = idx & 7;
        const float4 vi = *(const float4*)(Ibase + (size_t)row * W_ + g * 4);
        const float4 vj = *(const float4*)(Jbase + (size_t)row * W_ + g * 4);
        half4 hi, hj;
        hi.x = (_Float16)vi.x; hi.y = (_Float16)vi.y; hi.z = (_Float16)vi.z; hi.w = (_Float16)vi.w;
        hj.x = (_Float16)vj.x; hj.y = (_Float16)vj.y; hj.z = (_Float16)vj.z; hj.w = (_Float16)vj.w;
        *(half4*)&sI[row][g * 4] = hi;
        *(half4*)&sJ[row][g * 4] = hj;
    }
    __syncthreads();

    // ---- compute: thread = (xg, yc); 4 x-cols, y-chunk of 6 ----
    const int xg = tid & 7;                  // 0..7
    const int yc = tid >> 3;                 // 0..31
    const int y0 = yc * YCH1;
    const int x4 = xg * 4;

    _Float16* Ap = A + (size_t)bz * A_ZSTRIDE + x0 + x4;

    float4 s[5];
#pragma unroll
    for (int c = 0; c < 5; ++c) s[c] = make_float4(0, 0, 0, 0);

#pragma unroll
    for (int j = 0; j < 8; ++j) {            // prime window [y0-4, y0+3]
        const int yin = y0 - 4 + j;          // yin <= y0+3 <= 189 < H_ always
        if (yin >= 0)
            acc_lds<+1>(s, *(const half4*)&sI[yin][x4], *(const half4*)&sJ[yin][x4]);
    }
#pragma unroll
    for (int k = 0; k < YCH1; ++k) {
        const int yi = y0 + k + 4;           // leading edge
        if (yi < H_)
            acc_lds<+1>(s, *(const half4*)&sI[yi][x4], *(const half4*)&sJ[yi][x4]);
        const int yo = y0 + k - 5;           // trailing edge
        if (yo >= 0)
            acc_lds<-1>(s, *(const half4*)&sI[yo][x4], *(const half4*)&sJ[yo][x4]);

        _Float16* Ay = Ap + (size_t)(y0 + k) * A_YSTRIDE;
#pragma unroll
        for (int c = 0; c < 5; ++c) {
            half4 h;
            h.x = (_Float16)s[c].x; h.y = (_Float16)s[c].y;
            h.z = (_Float16)s[c].z; h.w = (_Float16)s[c].w;
            *(half4*)(Ay + c * W_) = h;
        }
    }
}

// ---------------------------------------------------------------------------
// K2: fused z-window sum (fp32 running sums over interleaved fp16 A) +
// x-window (3x float4 LDS reads per channel over a padded row) + cc +
// reduction. Block = 8 rows x 40 lanes (320 thr); thread owns 4 x-columns,
// marches a z-chunk of 10. Single-buffered LDS (26.9 KB).
// ---------------------------------------------------------------------------
__global__ void k2_zxcc(const _Float16* __restrict__ A, double* __restrict__ acc) {
    __shared__ float sbuf[ROWS2][5][LROW];   // 26.88 KB
    __shared__ float red[512];
    const int tid = threadIdx.x;             // 0..319
    const int r   = tid / W4_;               // 0..7
    const int l   = tid - r * W4_;           // 0..39
    const int x4  = l * 4;
    const int blk = blockIdx.x;
    const int zc  = blk % NZC2;
    const int rp  = blk / NZC2;              // 0..47
    const int gy  = rp * ROWS2 + r;          // 0..383  (192%8==0: no b straddle)
    const int b   = gy / H_;
    const int yy  = gy - b * H_;
    const int z0  = zc * ZCH2;

    {   // zero LDS once (pads must be 0; interior overwritten every step)
        float* p = &sbuf[0][0][0];
        for (int i = tid; i < ROWS2 * 5 * LROW; i += ROWS2 * W4_) p[i] = 0.f;
    }

    const _Float16* Abase = A + (size_t)b * D_ * A_ZSTRIDE + (size_t)yy * A_YSTRIDE + x4;

    float4 s[5];
#pragma unroll
    for (int c = 0; c < 5; ++c) s[c] = make_float4(0, 0, 0, 0);
#pragma unroll
    for (int j = 0; j < 8; ++j) {            // prime [z0-4, z0+3]; z0+3 <= 153 < D_
        const int zi = z0 - 4 + j;
        if (zi >= 0) {
            const _Float16* Az = Abase + (size_t)zi * A_ZSTRIDE;
#pragma unroll
            for (int c = 0; c < 5; ++c)
                add4h(s[c], *(const half4*)(Az + c * W_));
        }
    }
    __syncthreads();                         // LDS zero visible

    float local = 0.f;
    for (int k = 0; k < ZCH2; ++k) {
        const int zi = z0 + k + 4;
        if (zi < D_) {
            const _Float16* Az = Abase + (size_t)zi * A_ZSTRIDE;
#pragma unroll
            for (int c = 0; c < 5; ++c)
                add4h(s[c], *(const half4*)(Az + c * W_));
        }
        const int zo = z0 + k - 5;
        if (zo >= 0) {
            const _Float16* Az = Abase + (size_t)zo * A_ZSTRIDE;
#pragma unroll
            for (int c = 0; c < 5; ++c)
                sub4h(s[c], *(const half4*)(Az + c * W_));
        }
#pragma unroll
        for (int c = 0; c < 5; ++c)
            *(float4*)&sbuf[r][c][PAD + x4] = s[c];
        __syncthreads();

        float4 S5[5];
#pragma unroll
        for (int c = 0; c < 5; ++c) {
            const float4 a0 = *(const float4*)&sbuf[r][c][x4];
            const float4 a1 = *(const float4*)&sbuf[r][c][x4 + 4];
            const float4 a2 = *(const float4*)&sbuf[r][c][x4 + 8];
            const float o0 = a0.x + a0.y + a0.z + a0.w + a1.x + a1.y + a1.z + a1.w + a2.x;
            const float o1 = o0 - a0.x + a2.y;
            const float o2 = o1 - a0.y + a2.z;
            const float o3 = o2 - a0.z + a2.w;
            S5[c] = make_float4(o0, o1, o2, o3);
        }
        const float inv9 = 1.0f / 9.0f;
        {
            const float cr = S5[4].x - S5[1].x * S5[0].x * inv9;
            const float iv = S5[2].x - S5[0].x * S5[0].x * inv9;
            const float jv = S5[3].x - S5[1].x * S5[1].x * inv9;
            local += cr * cr / (iv * jv + 1e-5f);
        }
        {
            const float cr = S5[4].y - S5[1].y * S5[0].y * inv9;
            const float iv = S5[2].y - S5[0].y * S5[0].y * inv9;
            const float jv = S5[3].y - S5[1].y * S5[1].y * inv9;
            local += cr * cr / (iv * jv + 1e-5f);
        }
        {
            const float cr = S5[4].z - S5[1].z * S5[0].z * inv9;
            const float iv = S5[2].z - S5[0].z * S5[0].z * inv9;
            const float jv = S5[3].z - S5[1].z * S5[1].z * inv9;
            local += cr * cr / (iv * jv + 1e-5f);
        }
        {
            const float cr = S5[4].w - S5[1].w * S5[0].w * inv9;
            const float iv = S5[2].w - S5[0].w * S5[0].w * inv9;
            const float jv = S5[3].w - S5[1].w * S5[1].w * inv9;
            local += cr * cr / (iv * jv + 1e-5f);
        }
        __syncthreads();                     // WAR: next step overwrites sbuf
    }

    red[tid] = local;
    if (tid < 192) red[320 + tid] = 0.f;
    __syncthreads();
    for (int off = 256; off > 0; off >>= 1) {
        if (tid < off) red[tid] += red[tid + off];
        __syncthreads();
    }
    if (tid == 0) atomicAdd(acc, (double)red[0]);
}

// ---------------------------------------------------------------------------
// Fallback (workspace too small): direct clipped 9x9x9 sums per voxel.
// ---------------------------------------------------------------------------
__global__ void p_direct(const float* __restrict__ I, const float* __restrict__ J,
                         double* __restrict__ acc) {
    const long long idx = (long long)blockIdx.x * blockDim.x + threadIdx.x;
    float local = 0.f;
    if (idx < NV_) {
        const int x = (int)(idx % W_);
        long long t = idx / W_;
        const int y = (int)(t % H_);
        t /= H_;
        const int z = (int)(t % D_);
        const int b = (int)(t / D_);
        const int z0 = max(z - 4, 0), z1 = min(z + 4, D_ - 1);
        const int y0 = max(y - 4, 0), y1 = min(y + 4, H_ - 1);
        const int x0 = max(x - 4, 0), x1 = min(x + 4, W_ - 1);
        float sI = 0.f, sJ = 0.f, sI2 = 0.f, sJ2 = 0.f, sIJ = 0.f;
        for (int zz = z0; zz <= z1; ++zz)
            for (int yy = y0; yy <= y1; ++yy) {
                const size_t row = ((size_t)(b * D_ + zz) * H_ + yy) * W_;
                for (int xx = x0; xx <= x1; ++xx) {
                    const float a = I[row + xx];
                    const float bb = J[row + xx];
                    sI += a; sJ += bb; sI2 += a * a; sJ2 += bb * bb; sIJ += a * bb;
                }
            }
        const float inv9 = 1.0f / 9.0f;
        const float cross = sIJ - sJ * sI * inv9;
        const float iv    = sI2 - sI * sI * inv9;
        const float jv    = sJ2 - sJ * sJ * inv9;
        local = cross * cross / (iv * jv + 1e-5f);
    }
    __shared__ float red[256];
    red[threadIdx.x] = local;
    __syncthreads();
    for (int off = 128; off > 0; off >>= 1) {
        if (threadIdx.x < off) red[threadIdx.x] += red[threadIdx.x + off];
        __syncthreads();
    }
    if (threadIdx.x == 0) atomicAdd(acc, (double)red[0]);
}

__global__ void k_final(const double* __restrict__ acc, float* __restrict__ out) {
    out[0] = (float)(-(*acc) / (double)NV_);
}

extern "C" void kernel_launch(void* const* d_in, const int* in_sizes, int n_in,
                              void* d_out, int out_size, void* d_ws, size_t ws_size,
                              hipStream_t stream) {
    const float* I = (const float*)d_in[0];  // y_true
    const float* J = (const float*)d_in[1];  // y_pred
    float* out = (float*)d_out;

    const size_t needA = (size_t)5 * B_ * DHW_ * sizeof(_Float16);  // 98.3 MB
    if (ws_size >= 1024 + needA) {
        double* acc = (double*)d_ws;
        _Float16* A = (_Float16*)((char*)d_ws + 1024);
        k_zero<<<1, 1, 0, stream>>>(acc);
        k1_ysum<<<B_ * D_ * NXT, 256, 0, stream>>>(I, J, A);
        k2_zxcc<<<NZC2 * (B_ * H_ / ROWS2), ROWS2 * W4_, 0, stream>>>(A, acc);
        k_final<<<1, 1, 0, stream>>>(acc, out);
    } else if (ws_size >= sizeof(double)) {
        double* acc = (double*)d_ws;
        k_zero<<<1, 1, 0, stream>>>(acc);
        p_direct<<<(int)((NV_ + 255) / 256), 256, 0, stream>>>(I, J, acc);
        k_final<<<1, 1, 0, stream>>>(acc, out);
    }
}

// Round 14
// 80.883 us; speedup vs baseline: 2.9504x; 1.0112x over previous
//
#include <hip/hip_runtime.h>

// Shape: (B=2, C=1, D=160, H=192, W=160) fp32. win=9/dim, win_size=9 (faithful bug).
#define B_ 2
#define D_ 160
#define H_ 192
#define W_ 160
#define W4_ (W_ / 4)                         // 40
#define HW_ (H_ * W_)                        // 30720
#define DHW_ (D_ * HW_)                      // 4,915,200
#define NV_ ((long long)B_ * D_ * H_ * W_)   // 9,830,400

// K1 tiling: block = one (b,z) slice x 32-wide x-tile, full H staged in LDS.
#define XT 32
#define NXT (W_ / XT)       // 5
#define YCH1 6
#define NYC1 (H_ / YCH1)    // 32
#define SPAD 4              // LDS row pad (halves)

#define ROWS2 8
#define ZCH2 10
#define NZC2 (D_ / ZCH2)    // 16
#define PAD 4
#define LROW (W_ + 2 * PAD) // 168

// Block-local A layout: [bz][xt][y][c][x32] in _Float16.
//   Each (bz,xt) owns a contiguous SLAB of H*5*XT halves (61.4 KB) -> k1's
//   writes are full-line contiguous; RMW partial-line writes eliminated.
#define SLAB ((size_t)H_ * 5 * XT)           // 30720 halves
#define A_Z  ((size_t)NXT * SLAB)            // = 5*HW halves per z step

typedef _Float16 half4 __attribute__((ext_vector_type(4)));

__global__ void k_zero(double* acc) { *acc = 0.0; }

__device__ __forceinline__ void add4h(float4& d, const half4 v) {
    d.x += (float)v.x; d.y += (float)v.y; d.z += (float)v.z; d.w += (float)v.w;
}
__device__ __forceinline__ void sub4h(float4& d, const half4 v) {
    d.x -= (float)v.x; d.y -= (float)v.y; d.z -= (float)v.z; d.w -= (float)v.w;
}

// Accumulate (+/-) one staged row's 5 products into s[5] (4 x-cols).
template<int SGN>
__device__ __forceinline__ void acc_lds(float4 s[5], const half4 ha, const half4 hb) {
    const float4 a = make_float4((float)ha.x, (float)ha.y, (float)ha.z, (float)ha.w);
    const float4 b = make_float4((float)hb.x, (float)hb.y, (float)hb.z, (float)hb.w);
    if (SGN > 0) {
        s[0].x += a.x;     s[0].y += a.y;     s[0].z += a.z;     s[0].w += a.w;
        s[1].x += b.x;     s[1].y += b.y;     s[1].z += b.z;     s[1].w += b.w;
        s[2].x += a.x*a.x; s[2].y += a.y*a.y; s[2].z += a.z*a.z; s[2].w += a.w*a.w;
        s[3].x += b.x*b.x; s[3].y += b.y*b.y; s[3].z += b.z*b.z; s[3].w += b.w*b.w;
        s[4].x += a.x*b.x; s[4].y += a.y*b.y; s[4].z += a.z*b.z; s[4].w += a.w*b.w;
    } else {
        s[0].x -= a.x;     s[0].y -= a.y;     s[0].z -= a.z;     s[0].w -= a.w;
        s[1].x -= b.x;     s[1].y -= b.y;     s[1].z -= b.z;     s[1].w -= b.w;
        s[2].x -= a.x*a.x; s[2].y -= a.y*a.y; s[2].z -= a.z*a.z; s[2].w -= a.w*a.w;
        s[3].x -= b.x*b.x; s[3].y -= b.y*b.y; s[3].z -= b.z*b.z; s[3].w -= b.w*b.w;
        s[4].x -= a.x*b.x; s[4].y -= a.y*b.y; s[4].z -= a.z*b.z; s[4].w -= a.w*b.w;
    }
}

// ---------------------------------------------------------------------------
// K1: stage one (b,z) slice's 32-wide x-column pair (I,J, full H=192) into
// LDS as fp16 ONCE, then 8x32 threads run y-window running sums from LDS and
// store to the block-local contiguous A slab.
// ---------------------------------------------------------------------------
__global__ __launch_bounds__(256) void k1_ysum(const float* __restrict__ I,
                                               const float* __restrict__ J,
                                               _Float16* __restrict__ A) {
    __shared__ _Float16 sI[H_][XT + SPAD];   // 13.8 KB
    __shared__ _Float16 sJ[H_][XT + SPAD];   // 13.8 KB
    const int tid = threadIdx.x;             // 0..255
    const int xt  = blockIdx.x % NXT;
    const int bz  = blockIdx.x / NXT;        // b*D + z
    const int x0  = xt * XT;

    const float* Ibase = I + (size_t)bz * HW_ + x0;
    const float* Jbase = J + (size_t)bz * HW_ + x0;

    // ---- stage: 1536 float4 per map, 6 per thread per map ----
#pragma unroll
    for (int i = 0; i < 6; ++i) {
        const int idx = i * 256 + tid;       // 0..1535
        const int row = idx >> 3;            // /8 groups per row
        const int g   = idx & 7;
        const float4 vi = *(const float4*)(Ibase + (size_t)row * W_ + g * 4);
        const float4 vj = *(const float4*)(Jbase + (size_t)row * W_ + g * 4);
        half4 hi, hj;
        hi.x = (_Float16)vi.x; hi.y = (_Float16)vi.y; hi.z = (_Float16)vi.z; hi.w = (_Float16)vi.w;
        hj.x = (_Float16)vj.x; hj.y = (_Float16)vj.y; hj.z = (_Float16)vj.z; hj.w = (_Float16)vj.w;
        *(half4*)&sI[row][g * 4] = hi;
        *(half4*)&sJ[row][g * 4] = hj;
    }
    __syncthreads();

    // ---- compute: thread = (xg, yc); 4 x-cols, y-chunk of 6 ----
    const int xg = tid & 7;                  // 0..7
    const int yc = tid >> 3;                 // 0..31
    const int y0 = yc * YCH1;
    const int x4 = xg * 4;

    _Float16* Ap = A + ((size_t)bz * NXT + xt) * SLAB + x4;

    float4 s[5];
#pragma unroll
    for (int c = 0; c < 5; ++c) s[c] = make_float4(0, 0, 0, 0);

#pragma unroll
    for (int j = 0; j < 8; ++j) {            // prime window [y0-4, y0+3]
        const int yin = y0 - 4 + j;          // yin <= y0+3 <= 189 < H_ always
        if (yin >= 0)
            acc_lds<+1>(s, *(const half4*)&sI[yin][x4], *(const half4*)&sJ[yin][x4]);
    }
#pragma unroll
    for (int k = 0; k < YCH1; ++k) {
        const int yi = y0 + k + 4;           // leading edge
        if (yi < H_)
            acc_lds<+1>(s, *(const half4*)&sI[yi][x4], *(const half4*)&sJ[yi][x4]);
        const int yo = y0 + k - 5;           // trailing edge
        if (yo >= 0)
            acc_lds<-1>(s, *(const half4*)&sI[yo][x4], *(const half4*)&sJ[yo][x4]);

        _Float16* Ay = Ap + (size_t)(y0 + k) * (5 * XT);
#pragma unroll
        for (int c = 0; c < 5; ++c) {
            half4 h;
            h.x = (_Float16)s[c].x; h.y = (_Float16)s[c].y;
            h.z = (_Float16)s[c].z; h.w = (_Float16)s[c].w;
            *(half4*)(Ay + c * XT) = h;
        }
    }
}

// ---------------------------------------------------------------------------
// K2: fused z-window sum (fp32 running sums over block-local fp16 A) +
// x-window (3x float4 LDS reads per channel over a padded row) + cc +
// reduction. Block = 8 rows x 40 lanes (320 thr); thread owns 4 x-columns,
// marches a z-chunk of 10. Single-buffered LDS (26.9 KB).
// ---------------------------------------------------------------------------
__global__ void k2_zxcc(const _Float16* __restrict__ A, double* __restrict__ acc) {
    __shared__ float sbuf[ROWS2][5][LROW];   // 26.88 KB
    __shared__ float red[512];
    const int tid = threadIdx.x;             // 0..319
    const int r   = tid / W4_;               // 0..7
    const int l   = tid - r * W4_;           // 0..39
    const int x4  = l * 4;                   // global x
    const int xt  = l >> 3;                  // x-tile 0..4
    const int xl4 = (l & 7) * 4;             // local x within tile
    const int blk = blockIdx.x;
    const int zc  = blk % NZC2;
    const int rp  = blk / NZC2;              // 0..47
    const int gy  = rp * ROWS2 + r;          // 0..383  (192%8==0: no b straddle)
    const int b   = gy / H_;
    const int yy  = gy - b * H_;
    const int z0  = zc * ZCH2;

    {   // zero LDS once (pads must be 0; interior overwritten every step)
        float* p = &sbuf[0][0][0];
        for (int i = tid; i < ROWS2 * 5 * LROW; i += ROWS2 * W4_) p[i] = 0.f;
    }

    const _Float16* Abase = A + ((size_t)b * D_) * A_Z + (size_t)xt * SLAB
                              + (size_t)yy * (5 * XT) + xl4;

    float4 s[5];
#pragma unroll
    for (int c = 0; c < 5; ++c) s[c] = make_float4(0, 0, 0, 0);
#pragma unroll
    for (int j = 0; j < 8; ++j) {            // prime [z0-4, z0+3]; z0+3 <= 153 < D_
        const int zi = z0 - 4 + j;
        if (zi >= 0) {
            const _Float16* Az = Abase + (size_t)zi * A_Z;
#pragma unroll
            for (int c = 0; c < 5; ++c)
                add4h(s[c], *(const half4*)(Az + c * XT));
        }
    }
    __syncthreads();                         // LDS zero visible

    float local = 0.f;
    for (int k = 0; k < ZCH2; ++k) {
        const int zi = z0 + k + 4;
        if (zi < D_) {
            const _Float16* Az = Abase + (size_t)zi * A_Z;
#pragma unroll
            for (int c = 0; c < 5; ++c)
                add4h(s[c], *(const half4*)(Az + c * XT));
        }
        const int zo = z0 + k - 5;
        if (zo >= 0) {
            const _Float16* Az = Abase + (size_t)zo * A_Z;
#pragma unroll
            for (int c = 0; c < 5; ++c)
                sub4h(s[c], *(const half4*)(Az + c * XT));
        }
#pragma unroll
        for (int c = 0; c < 5; ++c)
            *(float4*)&sbuf[r][c][PAD + x4] = s[c];
        __syncthreads();

        float4 S5[5];
#pragma unroll
        for (int c = 0; c < 5; ++c) {
            const float4 a0 = *(const float4*)&sbuf[r][c][x4];
            const float4 a1 = *(const float4*)&sbuf[r][c][x4 + 4];
            const float4 a2 = *(const float4*)&sbuf[r][c][x4 + 8];
            const float o0 = a0.x + a0.y + a0.z + a0.w + a1.x + a1.y + a1.z + a1.w + a2.x;
            const float o1 = o0 - a0.x + a2.y;
            const float o2 = o1 - a0.y + a2.z;
            const float o3 = o2 - a0.z + a2.w;
            S5[c] = make_float4(o0, o1, o2, o3);
        }
        const float inv9 = 1.0f / 9.0f;
        {
            const float cr = S5[4].x - S5[1].x * S5[0].x * inv9;
            const float iv = S5[2].x - S5[0].x * S5[0].x * inv9;
            const float jv = S5[3].x - S5[1].x * S5[1].x * inv9;
            local += cr * cr / (iv * jv + 1e-5f);
        }
        {
            const float cr = S5[4].y - S5[1].y * S5[0].y * inv9;
            const float iv = S5[2].y - S5[0].y * S5[0].y * inv9;
            const float jv = S5[3].y - S5[1].y * S5[1].y * inv9;
            local += cr * cr / (iv * jv + 1e-5f);
        }
        {
            const float cr = S5[4].z - S5[1].z * S5[0].z * inv9;
            const float iv = S5[2].z - S5[0].z * S5[0].z * inv9;
            const float jv = S5[3].z - S5[1].z * S5[1].z * inv9;
            local += cr * cr / (iv * jv + 1e-5f);
        }
        {
            const float cr = S5[4].w - S5[1].w * S5[0].w * inv9;
            const float iv = S5[2].w - S5[0].w * S5[0].w * inv9;
            const float jv = S5[3].w - S5[1].w * S5[1].w * inv9;
            local += cr * cr / (iv * jv + 1e-5f);
        }
        __syncthreads();                     // WAR: next step overwrites sbuf
    }

    red[tid] = local;
    if (tid < 192) red[320 + tid] = 0.f;
    __syncthreads();
    for (int off = 256; off > 0; off >>= 1) {
        if (tid < off) red[tid] += red[tid + off];
        __syncthreads();
    }
    if (tid == 0) atomicAdd(acc, (double)red[0]);
}

// ---------------------------------------------------------------------------
// Fallback (workspace too small): direct clipped 9x9x9 sums per voxel.
// ---------------------------------------------------------------------------
__global__ void p_direct(const float* __restrict__ I, const float* __restrict__ J,
                         double* __restrict__ acc) {
    const long long idx = (long long)blockIdx.x * blockDim.x + threadIdx.x;
    float local = 0.f;
    if (idx < NV_) {
        const int x = (int)(idx % W_);
        long long t = idx / W_;
        const int y = (int)(t % H_);
        t /= H_;
        const int z = (int)(t % D_);
        const int b = (int)(t / D_);
        const int z0 = max(z - 4, 0), z1 = min(z + 4, D_ - 1);
        const int y0 = max(y - 4, 0), y1 = min(y + 4, H_ - 1);
        const int x0 = max(x - 4, 0), x1 = min(x + 4, W_ - 1);
        float sI = 0.f, sJ = 0.f, sI2 = 0.f, sJ2 = 0.f, sIJ = 0.f;
        for (int zz = z0; zz <= z1; ++zz)
            for (int yy = y0; yy <= y1; ++yy) {
                const size_t row = ((size_t)(b * D_ + zz) * H_ + yy) * W_;
                for (int xx = x0; xx <= x1; ++xx) {
                    const float a = I[row + xx];
                    const float bb = J[row + xx];
                    sI += a; sJ += bb; sI2 += a * a; sJ2 += bb * bb; sIJ += a * bb;
                }
            }
        const float inv9 = 1.0f / 9.0f;
        const float cross = sIJ - sJ * sI * inv9;
        const float iv    = sI2 - sI * sI * inv9;
        const float jv    = sJ2 - sJ * sJ * inv9;
        local = cross * cross / (iv * jv + 1e-5f);
    }
    __shared__ float red[256];
    red[threadIdx.x] = local;
    __syncthreads();
    for (int off = 128; off > 0; off >>= 1) {
        if (threadIdx.x < off) red[threadIdx.x] += red[threadIdx.x + off];
        __syncthreads();
    }
    if (threadIdx.x == 0) atomicAdd(acc, (double)red[0]);
}

__global__ void k_final(const double* __restrict__ acc, float* __restrict__ out) {
    out[0] = (float)(-(*acc) / (double)NV_);
}

extern "C" void kernel_launch(void* const* d_in, const int* in_sizes, int n_in,
                              void* d_out, int out_size, void* d_ws, size_t ws_size,
                              hipStream_t stream) {
    const float* I = (const float*)d_in[0];  // y_true
    const float* J = (const float*)d_in[1];  // y_pred
    float* out = (float*)d_out;

    const size_t needA = (size_t)5 * B_ * DHW_ * sizeof(_Float16);  // 98.3 MB
    if (ws_size >= 1024 + needA) {
        double* acc = (double*)d_ws;
        _Float16* A = (_Float16*)((char*)d_ws + 1024);
        k_zero<<<1, 1, 0, stream>>>(acc);
        k1_ysum<<<B_ * D_ * NXT, 256, 0, stream>>>(I, J, A);
        k2_zxcc<<<NZC2 * (B_ * H_ / ROWS2), ROWS2 * W4_, 0, stream>>>(A, acc);
        k_final<<<1, 1, 0, stream>>>(acc, out);
    } else if (ws_size >= sizeof(double)) {
        double* acc = (double*)d_ws;
        k_zero<<<1, 1, 0, stream>>>(acc);
        p_direct<<<(int)((NV_ + 255) / 256), 256, 0, stream>>>(I, J, acc);
        k_final<<<1, 1, 0, stream>>>(acc, out);
    }
}